// Round 1
// baseline (189.901 us; speedup 1.0000x reference)
//
#include <hip/hip_runtime.h>
#include <hip/hip_fp16.h>

#define B_ 128
#define N_ 512
#define C_ 128
#define W_ 128
#define LDSW 136  // padded row stride in halves for 128-col LDS tiles (272B: stride 68 dwords -> 2-way bank alias, free)

typedef _Float16 f16;
typedef _Float16 f16x8 __attribute__((ext_vector_type(8)));
typedef _Float16 f16x4 __attribute__((ext_vector_type(4)));
typedef float f32x4 __attribute__((ext_vector_type(4)));

#define MFMA16(a, b, c) __builtin_amdgcn_mfma_f32_16x16x32_f16(a, b, c, 0, 0, 0)

// ---------------------------------------------------------------------------
// K0: transpose Wq/Wk/Wv (fp32 [C][W]) -> fp16 WT[w][c] in ws
// ---------------------------------------------------------------------------
__global__ __launch_bounds__(256) void prep_w(const float* __restrict__ Wq,
                                              const float* __restrict__ Wk,
                                              const float* __restrict__ Wv,
                                              f16* __restrict__ wT) {
  const float* src = blockIdx.x == 0 ? Wq : (blockIdx.x == 1 ? Wk : Wv);
  f16* dst = wT + (size_t)blockIdx.x * C_ * W_;
  const int t = threadIdx.x;
  for (int i = 0; i < 64; ++i) {
    int idx = t + 256 * i;          // 16384 elements
    int w = idx >> 7, c = idx & 127;
    dst[idx] = (f16)src[c * W_ + w];  // dst[w][c] = W[c][w]
  }
}

// ---------------------------------------------------------------------------
// K1: fused QKV projection. q,k row-major fp16 [b][n][w]; v stored transposed
//     vT[b][w][n]. One WG = 128 query rows, 4 waves x 32 rows each.
// ---------------------------------------------------------------------------
__global__ __launch_bounds__(256) void proj(const float* __restrict__ x,
                                            const float* __restrict__ bq,
                                            const float* __restrict__ bk,
                                            const float* __restrict__ bv,
                                            const f16* __restrict__ wT,
                                            f16* __restrict__ q,
                                            f16* __restrict__ k,
                                            f16* __restrict__ vT) {
  __shared__ f16 xs[128 * LDSW];
  __shared__ f16 wls[128 * LDSW];
  const int b = blockIdx.y, n0 = blockIdx.x * 128;
  const int t = threadIdx.x, wave = t >> 6, lane = t & 63;
  const int quad = lane >> 4, l15 = lane & 15;

  // stage x tile (rows n, cols c), fp32 -> fp16
  for (int i = 0; i < 16; ++i) {
    int idx = t + 256 * i;          // 4096 float4
    int row = idx >> 5, c4 = idx & 31;
    const float4 v = *reinterpret_cast<const float4*>(
        x + ((size_t)(b * N_ + n0 + row)) * C_ + c4 * 4);
    f16x4 h;
    h.x = (f16)v.x; h.y = (f16)v.y; h.z = (f16)v.z; h.w = (f16)v.w;
    *reinterpret_cast<f16x4*>(&xs[row * LDSW + c4 * 4]) = h;
  }
  __syncthreads();

  // A fragments: A[m = lane&15][kdim = quad*8+j], rows are x rows
  f16x8 af[2][4];
  for (int mt = 0; mt < 2; ++mt)
    for (int ks = 0; ks < 4; ++ks)
      af[mt][ks] = *reinterpret_cast<const f16x8*>(
          &xs[(wave * 32 + mt * 16 + l15) * LDSW + ks * 32 + quad * 8]);

  for (int ph = 0; ph < 3; ++ph) {
    __syncthreads();  // previous phase's B reads done before overwrite
    for (int i = 0; i < 8; ++i) {
      int idx = t + 256 * i;        // 2048 x 16B
      int row = idx >> 4, c16 = idx & 15;
      *reinterpret_cast<f16x8*>(&wls[row * LDSW + c16 * 8]) =
          *reinterpret_cast<const f16x8*>(wT + (size_t)ph * 16384 + idx * 8);
    }
    __syncthreads();

    f32x4 acc[2][8];
    for (int mt = 0; mt < 2; ++mt)
      for (int ct = 0; ct < 8; ++ct) acc[mt][ct] = {0.f, 0.f, 0.f, 0.f};

    for (int ct = 0; ct < 8; ++ct)
      for (int ks = 0; ks < 4; ++ks) {
        f16x8 bf = *reinterpret_cast<const f16x8*>(
            &wls[(ct * 16 + l15) * LDSW + ks * 32 + quad * 8]);
        acc[0][ct] = MFMA16(af[0][ks], bf, acc[0][ct]);
        acc[1][ct] = MFMA16(af[1][ks], bf, acc[1][ct]);
      }

    const float* bias = ph == 0 ? bq : (ph == 1 ? bk : bv);
    if (ph < 2) {
      f16* dst = ph == 0 ? q : k;
      for (int mt = 0; mt < 2; ++mt)
        for (int ct = 0; ct < 8; ++ct) {
          int wcol = ct * 16 + l15;
          float bb = bias[wcol];
          for (int r = 0; r < 4; ++r) {
            int n = n0 + wave * 32 + mt * 16 + quad * 4 + r;
            dst[((size_t)(b * N_ + n)) * W_ + wcol] = (f16)(acc[mt][ct][r] + bb);
          }
        }
    } else {
      // v: store transposed vT[b][w][n]; regs r are 4 consecutive n -> pack 8B
      for (int mt = 0; mt < 2; ++mt)
        for (int ct = 0; ct < 8; ++ct) {
          int wcol = ct * 16 + l15;
          float bb = bias[wcol];
          int n = n0 + wave * 32 + mt * 16 + quad * 4;
          f16x4 h;
          h.x = (f16)(acc[mt][ct][0] + bb);
          h.y = (f16)(acc[mt][ct][1] + bb);
          h.z = (f16)(acc[mt][ct][2] + bb);
          h.w = (f16)(acc[mt][ct][3] + bb);
          *reinterpret_cast<f16x4*>(&vT[((size_t)(b * W_ + wcol)) * N_ + n]) = h;
        }
    }
  }
}

// ---------------------------------------------------------------------------
// K2: S = Q K^T, fp16 S[b][m][n]. WG = 128x128 tile; K tile in LDS, Q frags
//     loaded direct from global (wave-private rows, held in regs).
// ---------------------------------------------------------------------------
__global__ __launch_bounds__(256) void scores(const f16* __restrict__ q,
                                              const f16* __restrict__ k,
                                              f16* __restrict__ S) {
  __shared__ f16 kls[128 * LDSW];
  const int b = blockIdx.z, m0 = blockIdx.y * 128, n0 = blockIdx.x * 128;
  const int t = threadIdx.x, wave = t >> 6, lane = t & 63;
  const int quad = lane >> 4, l15 = lane & 15;

  for (int i = 0; i < 8; ++i) {
    int idx = t + 256 * i;
    int row = idx >> 4, c16 = idx & 15;
    *reinterpret_cast<f16x8*>(&kls[row * LDSW + c16 * 8]) =
        *reinterpret_cast<const f16x8*>(
            k + ((size_t)(b * N_ + n0 + row)) * W_ + c16 * 8);
  }
  f16x8 af[2][4];
  for (int mt = 0; mt < 2; ++mt)
    for (int kk = 0; kk < 4; ++kk)
      af[mt][kk] = *reinterpret_cast<const f16x8*>(
          q + ((size_t)(b * N_ + m0 + wave * 32 + mt * 16 + l15)) * W_ +
          kk * 32 + quad * 8);
  __syncthreads();

  f32x4 acc[2][8];
  for (int mt = 0; mt < 2; ++mt)
    for (int ct = 0; ct < 8; ++ct) acc[mt][ct] = {0.f, 0.f, 0.f, 0.f};

  for (int ct = 0; ct < 8; ++ct)
    for (int kk = 0; kk < 4; ++kk) {
      f16x8 bf = *reinterpret_cast<const f16x8*>(
          &kls[(ct * 16 + l15) * LDSW + kk * 32 + quad * 8]);
      acc[0][ct] = MFMA16(af[0][kk], bf, acc[0][ct]);
      acc[1][ct] = MFMA16(af[1][kk], bf, acc[1][ct]);
    }

  for (int mt = 0; mt < 2; ++mt)
    for (int ct = 0; ct < 8; ++ct) {
      int n = n0 + ct * 16 + l15;
      for (int r = 0; r < 4; ++r) {
        int m = m0 + wave * 32 + mt * 16 + quad * 4 + r;
        S[((size_t)(b * N_ + m)) * N_ + n] = (f16)acc[mt][ct][r];
      }
    }
}

// ---------------------------------------------------------------------------
// K3: masked softmax, in place S -> P. One wave per row (8 fp16/lane).
//     Faithful: masked cols (n > valid_len[b]) get score -1e-6f (NOT -inf)
//     and participate in max/exp/sum.
// ---------------------------------------------------------------------------
__global__ __launch_bounds__(256) void softmax_k(f16* __restrict__ S,
                                                 const int* __restrict__ vlen) {
  const int t = threadIdx.x, wave = t >> 6, lane = t & 63;
  const int gid = blockIdx.x * 4 + wave;  // row id in [0, B*N)
  const int b = gid >> 9, m = gid & 511;
  const int vl = vlen[b];
  f16* row = S + ((size_t)(b * N_ + m)) * N_;

  f16x8 hv = *reinterpret_cast<const f16x8*>(row + lane * 8);
  float v[8];
  float mx = -3.4e38f;
  for (int j = 0; j < 8; ++j) {
    int n = lane * 8 + j;
    v[j] = (n > vl) ? -1e-6f : (float)hv[j];
    mx = fmaxf(mx, v[j]);
  }
  for (int off = 1; off < 64; off <<= 1) mx = fmaxf(mx, __shfl_xor(mx, off));
  float sm = 0.f;
  for (int j = 0; j < 8; ++j) {
    v[j] = __expf(v[j] - mx);
    sm += v[j];
  }
  for (int off = 1; off < 64; off <<= 1) sm += __shfl_xor(sm, off);
  float inv = 1.f / sm;
  f16x8 o;
  for (int j = 0; j < 8; ++j) o[j] = (f16)(v[j] * inv);
  *reinterpret_cast<f16x8*>(row + lane * 8) = o;
}

// ---------------------------------------------------------------------------
// K4: O = P V. WG = 128 query rows; Vt chunks (128w x 128n) staged in LDS,
//     P fragments direct from global. Output fp32 row-major -> d_out.
// ---------------------------------------------------------------------------
__global__ __launch_bounds__(256) void pv(const f16* __restrict__ P,
                                          const f16* __restrict__ vT,
                                          float* __restrict__ out) {
  __shared__ f16 vls[128 * LDSW];
  const int b = blockIdx.y, m0 = blockIdx.x * 128;
  const int t = threadIdx.x, wave = t >> 6, lane = t & 63;
  const int quad = lane >> 4, l15 = lane & 15;

  f32x4 acc[2][8];
  for (int mt = 0; mt < 2; ++mt)
    for (int wt = 0; wt < 8; ++wt) acc[mt][wt] = {0.f, 0.f, 0.f, 0.f};

  for (int ch = 0; ch < 4; ++ch) {
    const int n0 = ch * 128;
    if (ch) __syncthreads();  // previous chunk's B reads done
    for (int i = 0; i < 8; ++i) {
      int idx = t + 256 * i;
      int row = idx >> 4, c16 = idx & 15;  // row = w
      *reinterpret_cast<f16x8*>(&vls[row * LDSW + c16 * 8]) =
          *reinterpret_cast<const f16x8*>(
              vT + ((size_t)(b * W_ + row)) * N_ + n0 + c16 * 8);
    }
    f16x8 af[2][4];
    for (int mt = 0; mt < 2; ++mt)
      for (int kk = 0; kk < 4; ++kk)
        af[mt][kk] = *reinterpret_cast<const f16x8*>(
            P + ((size_t)(b * N_ + m0 + wave * 32 + mt * 16 + l15)) * N_ + n0 +
            kk * 32 + quad * 8);
    __syncthreads();

    for (int wt = 0; wt < 8; ++wt)
      for (int kk = 0; kk < 4; ++kk) {
        f16x8 bf = *reinterpret_cast<const f16x8*>(
            &vls[(wt * 16 + l15) * LDSW + kk * 32 + quad * 8]);
        acc[0][wt] = MFMA16(af[0][kk], bf, acc[0][wt]);
        acc[1][wt] = MFMA16(af[1][kk], bf, acc[1][wt]);
      }
  }

  for (int mt = 0; mt < 2; ++mt)
    for (int wt = 0; wt < 8; ++wt) {
      int w = wt * 16 + l15;
      for (int r = 0; r < 4; ++r) {
        int m = m0 + wave * 32 + mt * 16 + quad * 4 + r;
        out[((size_t)(b * N_ + m)) * W_ + w] = acc[mt][wt][r];
      }
    }
}

// ---------------------------------------------------------------------------
extern "C" void kernel_launch(void* const* d_in, const int* in_sizes, int n_in,
                              void* d_out, int out_size, void* d_ws,
                              size_t ws_size, hipStream_t stream) {
  const float* x  = (const float*)d_in[0];
  const float* Wq = (const float*)d_in[1];
  const float* bq = (const float*)d_in[2];
  const float* Wk = (const float*)d_in[3];
  const float* bk = (const float*)d_in[4];
  const float* Wv = (const float*)d_in[5];
  const float* bv = (const float*)d_in[6];
  const int* vlen = (const int*)d_in[7];
  float* out = (float*)d_out;

  char* ws = (char*)d_ws;
  // ws layout: [0, 96KB) WT x3 | 1MB: q (16MB) | k (16MB) | vT (16MB) | S/P (64MB)
  f16* wT = (f16*)ws;
  f16* q  = (f16*)(ws + (1u << 20));
  f16* k  = (f16*)(ws + (1u << 20) + (16u << 20));
  f16* vT = (f16*)(ws + (1u << 20) + (32u << 20));
  f16* S  = (f16*)(ws + (1u << 20) + (48u << 20));

  prep_w<<<3, 256, 0, stream>>>(Wq, Wk, Wv, wT);
  proj<<<dim3(4, 128), 256, 0, stream>>>(x, bq, bk, bv, wT, q, k, vT);
  scores<<<dim3(4, 4, 128), 256, 0, stream>>>(q, k, S);
  softmax_k<<<16384, 256, 0, stream>>>(S, vlen);
  pv<<<dim3(4, 128), 256, 0, stream>>>(S, vT, out);
}

// Round 2
// 146.348 us; speedup vs baseline: 1.2976x; 1.2976x over previous
//
#include <hip/hip_runtime.h>
#include <hip/hip_fp16.h>

#define B_ 128
#define N_ 512
#define C_ 128
#define W_ 128
#define LDSW 136  // padded row stride (halves) for 128-col LDS tiles

typedef _Float16 f16;
typedef _Float16 f16x8 __attribute__((ext_vector_type(8)));
typedef _Float16 f16x4 __attribute__((ext_vector_type(4)));
typedef float f32x4 __attribute__((ext_vector_type(4)));

#define MFMA16(a, b, c) __builtin_amdgcn_mfma_f32_16x16x32_f16(a, b, c, 0, 0, 0)

// ---------------------------------------------------------------------------
// K0: transpose Wq/Wk/Wv (fp32 [C][W]) -> fp16 WT[w][c] in ws
// ---------------------------------------------------------------------------
__global__ __launch_bounds__(256) void prep_w(const float* __restrict__ Wq,
                                              const float* __restrict__ Wk,
                                              const float* __restrict__ Wv,
                                              f16* __restrict__ wT) {
  const float* src = blockIdx.x == 0 ? Wq : (blockIdx.x == 1 ? Wk : Wv);
  f16* dst = wT + (size_t)blockIdx.x * C_ * W_;
  const int t = threadIdx.x;
  for (int i = 0; i < 64; ++i) {
    int idx = t + 256 * i;
    int w = idx >> 7, c = idx & 127;
    dst[idx] = (f16)src[c * W_ + w];
  }
}

// ---------------------------------------------------------------------------
// K1: fused QKV projection. q,k row-major fp16 [b][n][w]; v transposed
//     vT[b][w][n]. One WG = 128 rows, 4 waves x 32 rows.
// ---------------------------------------------------------------------------
__global__ __launch_bounds__(256) void proj(const float* __restrict__ x,
                                            const float* __restrict__ bq,
                                            const float* __restrict__ bk,
                                            const float* __restrict__ bv,
                                            const f16* __restrict__ wT,
                                            f16* __restrict__ q,
                                            f16* __restrict__ k,
                                            f16* __restrict__ vT) {
  __shared__ f16 xs[128 * LDSW];
  __shared__ f16 wls[128 * LDSW];
  const int b = blockIdx.y, n0 = blockIdx.x * 128;
  const int t = threadIdx.x, wave = t >> 6, lane = t & 63;
  const int quad = lane >> 4, l15 = lane & 15;

  for (int i = 0; i < 16; ++i) {
    int idx = t + 256 * i;
    int row = idx >> 5, c4 = idx & 31;
    const float4 v = *reinterpret_cast<const float4*>(
        x + ((size_t)(b * N_ + n0 + row)) * C_ + c4 * 4);
    f16x4 h;
    h.x = (f16)v.x; h.y = (f16)v.y; h.z = (f16)v.z; h.w = (f16)v.w;
    *reinterpret_cast<f16x4*>(&xs[row * LDSW + c4 * 4]) = h;
  }
  __syncthreads();

  f16x8 af[2][4];
  for (int mt = 0; mt < 2; ++mt)
    for (int ks = 0; ks < 4; ++ks)
      af[mt][ks] = *reinterpret_cast<const f16x8*>(
          &xs[(wave * 32 + mt * 16 + l15) * LDSW + ks * 32 + quad * 8]);

  for (int ph = 0; ph < 3; ++ph) {
    __syncthreads();
    for (int i = 0; i < 8; ++i) {
      int idx = t + 256 * i;
      int row = idx >> 4, c16 = idx & 15;
      *reinterpret_cast<f16x8*>(&wls[row * LDSW + c16 * 8]) =
          *reinterpret_cast<const f16x8*>(wT + (size_t)ph * 16384 + idx * 8);
    }
    __syncthreads();

    f32x4 acc[2][8];
    for (int mt = 0; mt < 2; ++mt)
      for (int ct = 0; ct < 8; ++ct) acc[mt][ct] = {0.f, 0.f, 0.f, 0.f};

    for (int ct = 0; ct < 8; ++ct)
      for (int ks = 0; ks < 4; ++ks) {
        f16x8 bf = *reinterpret_cast<const f16x8*>(
            &wls[(ct * 16 + l15) * LDSW + ks * 32 + quad * 8]);
        acc[0][ct] = MFMA16(af[0][ks], bf, acc[0][ct]);
        acc[1][ct] = MFMA16(af[1][ks], bf, acc[1][ct]);
      }

    const float* bias = ph == 0 ? bq : (ph == 1 ? bk : bv);
    if (ph < 2) {
      f16* dst = ph == 0 ? q : k;
      for (int mt = 0; mt < 2; ++mt)
        for (int ct = 0; ct < 8; ++ct) {
          int wcol = ct * 16 + l15;
          float bb = bias[wcol];
          for (int r = 0; r < 4; ++r) {
            int n = n0 + wave * 32 + mt * 16 + quad * 4 + r;
            dst[((size_t)(b * N_ + n)) * W_ + wcol] = (f16)(acc[mt][ct][r] + bb);
          }
        }
    } else {
      for (int mt = 0; mt < 2; ++mt)
        for (int ct = 0; ct < 8; ++ct) {
          int wcol = ct * 16 + l15;
          float bb = bias[wcol];
          int n = n0 + wave * 32 + mt * 16 + quad * 4;
          f16x4 h;
          h.x = (f16)(acc[mt][ct][0] + bb);
          h.y = (f16)(acc[mt][ct][1] + bb);
          h.z = (f16)(acc[mt][ct][2] + bb);
          h.w = (f16)(acc[mt][ct][3] + bb);
          *reinterpret_cast<f16x4*>(&vT[((size_t)(b * W_ + wcol)) * N_ + n]) = h;
        }
    }
  }
}

// ---------------------------------------------------------------------------
// K2: flash attention. One WG per (b, 128-row m-tile); 4 K/V chunks of 128.
//     Computes S^T = K.Q^T so P^T packs to LDS with b64 writes and PV runs
//     as O^T = V^T.P^T (A=vT direct from global, B=P^T via ds_read_b128).
//     Online softmax per m-column (ct,l15), stats replicated across quads.
//     Faithful mask: key n > valid_len[b] gets score -1e-6f (participates).
// ---------------------------------------------------------------------------
__global__ __launch_bounds__(256, 2) void flash(const f16* __restrict__ q,
                                                const f16* __restrict__ k,
                                                const f16* __restrict__ vT,
                                                const int* __restrict__ vlen,
                                                float* __restrict__ out) {
  __shared__ f16 qls[128 * LDSW];
  __shared__ f16 pls[128 * LDSW];
  const int b = blockIdx.x, m0 = blockIdx.y * 128;  // x=b: same-b WGs share XCD
  const int t = threadIdx.x, wave = t >> 6, lane = t & 63;
  const int quad = lane >> 4, l15 = lane & 15;
  const int vl = vlen[b];

  // stage Q tile [m][c] once (reused all 4 chunks)
  for (int i = 0; i < 8; ++i) {
    int idx = t + 256 * i;
    int row = idx >> 4, c16 = idx & 15;
    *reinterpret_cast<f16x8*>(&qls[row * LDSW + c16 * 8]) =
        *reinterpret_cast<const f16x8*>(
            q + ((size_t)(b * N_ + m0 + row)) * W_ + c16 * 8);
  }
  __syncthreads();

  f32x4 oacc[2][8];
  for (int mt = 0; mt < 2; ++mt)
    for (int ct = 0; ct < 8; ++ct) oacc[mt][ct] = {0.f, 0.f, 0.f, 0.f};
  float mrun[8], lrun[8];
  for (int ct = 0; ct < 8; ++ct) { mrun[ct] = -3.4e38f; lrun[ct] = 0.f; }

  for (int j = 0; j < 4; ++j) {
    const int n0 = j * 128;

    // K A-fragments direct from global: A[n-row=l15][c=kt*32+quad*8]
    f16x8 kf[2][4];
    for (int mt = 0; mt < 2; ++mt)
      for (int kt = 0; kt < 4; ++kt)
        kf[mt][kt] = *reinterpret_cast<const f16x8*>(
            k + ((size_t)(b * N_ + n0 + wave * 32 + mt * 16 + l15)) * W_ +
            kt * 32 + quad * 8);

    // S^T chunk: rows n (wave-owned), cols m
    f32x4 sacc[2][8];
    for (int mt = 0; mt < 2; ++mt)
      for (int ct = 0; ct < 8; ++ct) sacc[mt][ct] = {0.f, 0.f, 0.f, 0.f};
    for (int ct = 0; ct < 8; ++ct)
      for (int kt = 0; kt < 4; ++kt) {
        f16x8 bf = *reinterpret_cast<const f16x8*>(
            &qls[(ct * 16 + l15) * LDSW + kt * 32 + quad * 8]);
        sacc[0][ct] = MFMA16(kf[0][kt], bf, sacc[0][ct]);
        sacc[1][ct] = MFMA16(kf[1][kt], bf, sacc[1][ct]);
      }

    // mask: key index n = row of S^T
    for (int mt = 0; mt < 2; ++mt)
      for (int r = 0; r < 4; ++r) {
        int n = n0 + wave * 32 + mt * 16 + quad * 4 + r;
        if (n > vl)
          for (int ct = 0; ct < 8; ++ct) sacc[mt][ct][r] = -1e-6f;
      }

    // online softmax per m-column (this chunk covers rows n only within wave;
    // cross-quad reduction completes the 32-row wave slab... plus other waves'
    // rows are in OTHER m... no: each wave covers its own n rows but ALL m
    // columns, and different waves handle different n — stats must combine
    // across waves? No: each wave's oacc covers its own w rows but all m, and
    // each wave processes ALL n chunks over j; within a chunk a wave only sees
    // its own 32 n-rows. Cross-wave n coverage happens because EVERY wave
    // iterates all 4 chunks... but within chunk j, wave w sees n-rows
    // [n0+wave*32, n0+wave*32+32) only -- waves see DIFFERENT keys!
    // Fix: chunk = 128 keys, the 4 waves TOGETHER cover it; but P^T in LDS is
    // written by all waves and PV contracts over the full 128 -- so P must be
    // softmaxed with stats over the full 128-key chunk. Stats from the wave's
    // 32 rows alone are incomplete... BUT exp(s - mnew) with a PER-WAVE mnew
    // is still a valid online softmax AS LONG AS the rescale factor applied
    // to oacc matches the stats used for the p values this wave CONTRIBUTES.
    // It does not: P^T rows from different waves would use different mnew.
    // => must reduce stats across waves. Cross-wave = cross-lane beyond 64:
    // use LDS. Simpler correct alternative: make mnew GLOBALLY SAFE without
    // cross-wave comms: scores are bounded; use a FIXED max proxy M=0? exp
    // overflow risk: scores ~ N(0, 128) -> |s| up to ~60; exp(60) overflows.
    // So we DO need the true chunk max across waves -> small LDS reduction.
    float cm[8];
    for (int ct = 0; ct < 8; ++ct) {
      float c0 = fmaxf(fmaxf(sacc[0][ct][0], sacc[0][ct][1]),
                       fmaxf(sacc[0][ct][2], sacc[0][ct][3]));
      float c1 = fmaxf(fmaxf(sacc[1][ct][0], sacc[1][ct][1]),
                       fmaxf(sacc[1][ct][2], sacc[1][ct][3]));
      float c = fmaxf(c0, c1);
      c = fmaxf(c, __shfl_xor(c, 16));
      c = fmaxf(c, __shfl_xor(c, 32));
      cm[ct] = c;  // wave-local max over its 32 n-rows, per m-col
    }
    // cross-wave max via LDS (4 waves x 128 m-cols)
    __shared__ float redbuf[4 * 128];
    __syncthreads();  // also fences previous chunk's pls reads
    if (quad == 0)
      for (int ct = 0; ct < 8; ++ct) redbuf[wave * 128 + ct * 16 + l15] = cm[ct];
    __syncthreads();
    float alpha[8];
    for (int ct = 0; ct < 8; ++ct) {
      int mcol = ct * 16 + l15;
      float c = fmaxf(fmaxf(redbuf[mcol], redbuf[128 + mcol]),
                      fmaxf(redbuf[256 + mcol], redbuf[384 + mcol]));
      float mnew = fmaxf(mrun[ct], c);
      alpha[ct] = __expf(mrun[ct] - mnew);
      mrun[ct] = mnew;
    }
    // p = exp(s - mnew); wave-local column sums
    float ls[8];
    for (int ct = 0; ct < 8; ++ct) {
      float s = 0.f;
      for (int mt = 0; mt < 2; ++mt)
        for (int r = 0; r < 4; ++r) {
          float p = __expf(sacc[mt][ct][r] - mrun[ct]);
          sacc[mt][ct][r] = p;
          s += p;
        }
      s += __shfl_xor(s, 16);
      s += __shfl_xor(s, 32);
      ls[ct] = s;
    }
    if (quad == 0)
      for (int ct = 0; ct < 8; ++ct) redbuf[wave * 128 + ct * 16 + l15] = ls[ct];
    // write P^T[m][n]: f16x4 of 4 consecutive n at fixed m
    for (int mt = 0; mt < 2; ++mt)
      for (int ct = 0; ct < 8; ++ct) {
        f16x4 h;
        h.x = (f16)sacc[mt][ct][0];
        h.y = (f16)sacc[mt][ct][1];
        h.z = (f16)sacc[mt][ct][2];
        h.w = (f16)sacc[mt][ct][3];
        *reinterpret_cast<f16x4*>(
            &pls[(ct * 16 + l15) * LDSW + wave * 32 + mt * 16 + quad * 4]) = h;
      }
    // V A-fragments direct from global (overlaps LDS writes)
    f16x8 vf[2][4];
    for (int mt = 0; mt < 2; ++mt)
      for (int kt = 0; kt < 4; ++kt)
        vf[mt][kt] = *reinterpret_cast<const f16x8*>(
            vT + ((size_t)(b * W_ + wave * 32 + mt * 16 + l15)) * N_ + n0 +
            kt * 32 + quad * 8);
    __syncthreads();  // pls + redbuf visible
    // finish l update with cross-wave sums; rescale O
    for (int ct = 0; ct < 8; ++ct) {
      int mcol = ct * 16 + l15;
      float s = redbuf[mcol] + redbuf[128 + mcol] + redbuf[256 + mcol] +
                redbuf[384 + mcol];
      lrun[ct] = lrun[ct] * alpha[ct] + s;
      oacc[0][ct] *= alpha[ct];
      oacc[1][ct] *= alpha[ct];
    }
    // PV: O^T += V^T . P^T
    for (int ct = 0; ct < 8; ++ct)
      for (int kt = 0; kt < 4; ++kt) {
        f16x8 bf = *reinterpret_cast<const f16x8*>(
            &pls[(ct * 16 + l15) * LDSW + kt * 32 + quad * 8]);
        oacc[0][ct] = MFMA16(vf[0][kt], bf, oacc[0][ct]);
        oacc[1][ct] = MFMA16(vf[1][kt], bf, oacc[1][ct]);
      }
  }

  // epilogue: divide by l, store O[m][w] from O^T regs (4 consecutive w)
  for (int ct = 0; ct < 8; ++ct) {
    float inv = 1.f / lrun[ct];
    int m = m0 + ct * 16 + l15;
    for (int mt = 0; mt < 2; ++mt) {
      int w = wave * 32 + mt * 16 + quad * 4;
      float4 o;
      o.x = oacc[mt][ct][0] * inv;
      o.y = oacc[mt][ct][1] * inv;
      o.z = oacc[mt][ct][2] * inv;
      o.w = oacc[mt][ct][3] * inv;
      *reinterpret_cast<float4*>(&out[((size_t)(b * N_ + m)) * W_ + w]) = o;
    }
  }
}

// ---------------------------------------------------------------------------
extern "C" void kernel_launch(void* const* d_in, const int* in_sizes, int n_in,
                              void* d_out, int out_size, void* d_ws,
                              size_t ws_size, hipStream_t stream) {
  const float* x  = (const float*)d_in[0];
  const float* Wq = (const float*)d_in[1];
  const float* bq = (const float*)d_in[2];
  const float* Wk = (const float*)d_in[3];
  const float* bk = (const float*)d_in[4];
  const float* Wv = (const float*)d_in[5];
  const float* bv = (const float*)d_in[6];
  const int* vlen = (const int*)d_in[7];
  float* out = (float*)d_out;

  char* ws = (char*)d_ws;
  f16* wT = (f16*)ws;
  f16* q  = (f16*)(ws + (1u << 20));
  f16* k  = (f16*)(ws + (1u << 20) + (16u << 20));
  f16* vT = (f16*)(ws + (1u << 20) + (32u << 20));

  prep_w<<<3, 256, 0, stream>>>(Wq, Wk, Wv, wT);
  proj<<<dim3(4, 128), 256, 0, stream>>>(x, bq, bk, bv, wT, q, k, vT);
  flash<<<dim3(128, 4), 256, 0, stream>>>(q, k, vT, vlen, out);
}